// Round 5
// baseline (2468.614 us; speedup 1.0000x reference)
//
#include <hip/hip_runtime.h>
#include <math.h>

#define Bq 16
#define Hc 384
#define Tt 2048
#define N2 32
#define LYR 6
#define HFq 1536
#define TWOH 768
#define CHUNK 64
#define NCH (Tt/CHUNK)   // 32

typedef __bf16 bf16x8 __attribute__((ext_vector_type(8)));
typedef float floatx4 __attribute__((ext_vector_type(4)));

__device__ __forceinline__ unsigned short bfbits(float f) {
  union { float f; unsigned u; } x; x.f = f;
  return (unsigned short)((x.u + 0x7FFF + ((x.u >> 16) & 1)) >> 16);
}

// ---------------- param precompute (fp64 for accuracy) ----------------
__global__ void param_kernel(const float* __restrict__ log_dt,
                             const float* __restrict__ A_re, const float* __restrict__ A_im,
                             const float* __restrict__ C_re, const float* __restrict__ C_im,
                             float* __restrict__ wre, float* __restrict__ wim,
                             float* __restrict__ cdre, float* __restrict__ cdim,
                             float* __restrict__ wSre, float* __restrict__ wSim) {
  int idx = blockIdx.x * blockDim.x + threadIdx.x;
  if (idx >= LYR * Hc * N2) return;
  int hn = idx / N2;
  double dt = exp((double)log_dt[hn]);
  double are = (double)A_re[idx], aim = (double)A_im[idx];
  double dre = are * dt, dimv = aim * dt;
  double er = exp(dre);
  double wr = er * cos(dimv), wi_ = er * sin(dimv);
  double den = are * are + aim * aim;
  double nr = wr - 1.0, ni = wi_;
  double qr = (nr * are + ni * aim) / den;
  double qi = (ni * are - nr * aim) / den;
  double cr = (double)C_re[idx], ci = (double)C_im[idx];
  cdre[idx] = (float)(2.0 * (cr * qr - ci * qi));
  cdim[idx] = (float)(2.0 * (cr * qi + ci * qr));
  wre[idx] = (float)wr; wim[idx] = (float)wi_;
  double es = exp(dre * (double)CHUNK);
  wSre[idx] = (float)(es * cos(dimv * (double)CHUNK));
  wSim[idx] = (float)(es * sin(dimv * (double)CHUNK));
}

// ---------------- weight fp32 -> bf16 (RNE) ----------------
__global__ void cvt_bf16_kernel(const float* __restrict__ in, unsigned short* __restrict__ out,
                                int n4) {
  int idx = blockIdx.x * 256 + threadIdx.x;
  if (idx >= n4) return;
  float4 v = ((const float4*)in)[idx];
  ushort4 o;
  o.x = bfbits(v.x); o.y = bfbits(v.y); o.z = bfbits(v.z); o.w = bfbits(v.w);
  ((ushort4*)out)[idx] = o;
}

// ---------------- transpose (B,C,T) -> (B,T,C) ----------------
__global__ __launch_bounds__(256) void transpose_fwd(const float* __restrict__ in,
                                                     float* __restrict__ out) {
  __shared__ float tile[32][33];
  int tx = threadIdx.x, ty = threadIdx.y;
  int t0 = blockIdx.x * 32, c0 = blockIdx.y * 32, b = blockIdx.z;
#pragma unroll
  for (int k = 0; k < 4; k++)
    tile[ty + 8 * k][tx] = in[((size_t)(b * Hc + c0 + ty + 8 * k)) * Tt + t0 + tx];
  __syncthreads();
#pragma unroll
  for (int k = 0; k < 4; k++)
    out[((size_t)(b * Tt + t0 + ty + 8 * k)) * Hc + c0 + tx] = tile[tx][ty + 8 * k];
}

// ---------------- transpose (B,T,C) -> (B,C,T) with mask ----------------
__global__ __launch_bounds__(256) void transpose_bwd(const float* __restrict__ in,
                                                     const float* __restrict__ mask,
                                                     float* __restrict__ out) {
  __shared__ float tile[32][33];
  int tx = threadIdx.x, ty = threadIdx.y;
  int t0 = blockIdx.x * 32, c0 = blockIdx.y * 32, b = blockIdx.z;
#pragma unroll
  for (int k = 0; k < 4; k++)
    tile[ty + 8 * k][tx] = in[((size_t)(b * Tt + t0 + ty + 8 * k)) * Hc + c0 + tx];
  __syncthreads();
  float mv = mask[(size_t)b * Tt + t0 + tx];
#pragma unroll
  for (int k = 0; k < 4; k++)
    out[((size_t)(b * Hc + c0 + ty + 8 * k)) * Tt + t0 + tx] = tile[tx][ty + 8 * k] * mv;
}

// ---------------- scan phase 1: chunk-local states ----------------
// lane pair (h, half): each thread handles 16 of the 32 modes
__global__ __launch_bounds__(256) void scan_local_t(
    const float* __restrict__ xT, const float* __restrict__ mask,
    const float* __restrict__ wre, const float* __restrict__ wim,
    float* __restrict__ states) {
  int tid = threadIdx.x;
  int h2 = tid >> 1, half = tid & 1;
  int hg = blockIdx.y * 128 + h2;
  int c = blockIdx.x, b = blockIdx.z;
  int nb = half * 16;
  float wr[16], wi[16], sr[16], si[16];
#pragma unroll
  for (int n = 0; n < 16; n++) {
    wr[n] = wre[hg * N2 + nb + n]; wi[n] = wim[hg * N2 + nb + n];
    sr[n] = 0.f; si[n] = 0.f;
  }
  const float* xp = xT + ((size_t)(b * Tt + c * CHUNK)) * Hc + hg;
  const float* mp = mask + (size_t)b * Tt + c * CHUNK;
#pragma unroll 4
  for (int t = 0; t < CHUNK; t++) {
    float u = xp[(size_t)t * Hc] * mp[t];
#pragma unroll
    for (int n = 0; n < 16; n++) {
      float s0 = sr[n];
      sr[n] = fmaf(wr[n], s0, fmaf(-wi[n], si[n], u));
      si[n] = fmaf(wr[n], si[n], wi[n] * s0);
    }
  }
  float* sp = states + (((size_t)(b * Hc + hg)) * NCH + c) * (2 * N2) + 2 * nb;
#pragma unroll
  for (int n = 0; n < 16; n++) { sp[2 * n] = sr[n]; sp[2 * n + 1] = si[n]; }
}

// ---------------- scan phase 2: prefix over chunks, thread per (b,h,n) ----------------
__global__ __launch_bounds__(256) void scan_prefix(
    float* __restrict__ states,
    const float* __restrict__ wSre, const float* __restrict__ wSim) {
  int tid = blockIdx.x * 256 + threadIdx.x;  // (b*Hc + h)*N2 + n
  if (tid >= Bq * Hc * N2) return;
  int n = tid & (N2 - 1);
  int h = (tid >> 5) % Hc;
  int row = tid >> 5;  // b*Hc + h
  float wr = wSre[h * N2 + n], wi = wSim[h * N2 + n];
  float cr = 0.f, ci = 0.f;
  float* base = states + (size_t)row * NCH * 2 * N2 + 2 * n;
  for (int c = 0; c < NCH; c++) {
    float2 s = *(float2*)(base + (size_t)c * 2 * N2);
    *(float2*)(base + (size_t)c * 2 * N2) = make_float2(cr, ci);
    float c0 = cr;
    cr = fmaf(wr, c0, fmaf(-wi, ci, s.x));
    ci = fmaf(wr, ci, fmaf(wi, c0, s.y));
  }
}

// ---------------- scan phase 3: y = gelu(ssm + D*x), bf16 out ----------------
// pair-split modes; even/odd t GELU split (both lanes hold full accT after shfl)
__global__ __launch_bounds__(256) void scan_out_t(
    const float* __restrict__ xT, const float* __restrict__ mask,
    const float* __restrict__ wre, const float* __restrict__ wim,
    const float* __restrict__ cdre, const float* __restrict__ cdim,
    const float* __restrict__ Dv, const float* __restrict__ states,
    unsigned short* __restrict__ ybf) {
  int tid = threadIdx.x;
  int h2 = tid >> 1, half = tid & 1;
  int hg = blockIdx.y * 128 + h2;
  int c = blockIdx.x, b = blockIdx.z;
  int nb = half * 16;
  float wr[16], wi[16], cdr[16], cdi[16], sr[16], si[16];
  const float* sp = states + (((size_t)(b * Hc + hg)) * NCH + c) * (2 * N2) + 2 * nb;
#pragma unroll
  for (int n = 0; n < 16; n++) {
    wr[n] = wre[hg * N2 + nb + n];  wi[n] = wim[hg * N2 + nb + n];
    cdr[n] = cdre[hg * N2 + nb + n]; cdi[n] = cdim[hg * N2 + nb + n];
    sr[n] = sp[2 * n]; si[n] = sp[2 * n + 1];
  }
  float d = Dv[hg];
  const float* xp = xT + ((size_t)(b * Tt + c * CHUNK)) * Hc + hg;
  const float* mp = mask + (size_t)b * Tt + c * CHUNK;
  unsigned short* yp = ybf + ((size_t)(b * Tt + c * CHUNK)) * Hc + hg;
#pragma unroll 2
  for (int t = 0; t < CHUNK; t += 2) {
    float u0 = xp[(size_t)t * Hc] * mp[t];
    float u1 = xp[(size_t)(t + 1) * Hc] * mp[t + 1];
    float acc0 = 0.f, acc1 = 0.f;
#pragma unroll
    for (int n = 0; n < 16; n++) {
      float s0 = sr[n];
      sr[n] = fmaf(wr[n], s0, fmaf(-wi[n], si[n], u0));
      si[n] = fmaf(wr[n], si[n], wi[n] * s0);
      acc0 = fmaf(cdr[n], sr[n], fmaf(-cdi[n], si[n], acc0));
    }
#pragma unroll
    for (int n = 0; n < 16; n++) {
      float s0 = sr[n];
      sr[n] = fmaf(wr[n], s0, fmaf(-wi[n], si[n], u1));
      si[n] = fmaf(wr[n], si[n], wi[n] * s0);
      acc1 = fmaf(cdr[n], sr[n], fmaf(-cdi[n], si[n], acc1));
    }
    float accT0 = acc0 + __shfl_xor(acc0, 1);
    float accT1 = acc1 + __shfl_xor(acc1, 1);
    // lane half handles timestep t+half (both lanes have both full sums)
    float u = half ? u1 : u0;
    float accT = half ? accT1 : accT0;
    float v = fmaf(d, u, accT);
    v = 0.5f * v * (1.0f + erff(v * 0.70710678118654752f));
    yp[(size_t)(t + half) * Hc] = bfbits(v);
  }
}

// ---------------- MFMA GEMM: out(B,T,N) = act(B,T,K) x W(N,K)^T ----------------
// EPI 0: outf = acc + bias                (fp32)
// EPI 1: outb = relu(acc + bias) * mask   (bf16)
// EPI 2: GLU: W has 2N rows; outf = (a+ba)*sigmoid(g+bg)  (fp32)
template <int EPI>
__global__ __launch_bounds__(256) void mfma_gemm(
    const __bf16* __restrict__ act, const __bf16* __restrict__ W,
    const float* __restrict__ bias, const float* __restrict__ mask,
    float* __restrict__ outf, unsigned short* __restrict__ outb,
    int K, int NOUT) {
  __shared__ __bf16 As[128][32];
  __shared__ __bf16 Bs[128][32];
  __shared__ __bf16 Bs2[(EPI == 2) ? 128 : 1][32];
  int tid = threadIdx.x;
  int b = blockIdx.z;
  int t0 = blockIdx.x * 128, n0 = blockIdx.y * 128;
  int wave = tid >> 6, lane = tid & 63, l16 = lane & 15, quad = lane >> 4;
  int wm = wave >> 1, wn = wave & 1;
  int sr = tid >> 2, sk = (tid & 3) * 8;

  floatx4 acc[4][4];
  floatx4 accg[(EPI == 2) ? 4 : 1][4];
#pragma unroll
  for (int i = 0; i < 4; i++)
#pragma unroll
    for (int j = 0; j < 4; j++) {
      acc[i][j] = (floatx4){0.f, 0.f, 0.f, 0.f};
      if constexpr (EPI == 2) accg[i][j] = (floatx4){0.f, 0.f, 0.f, 0.f};
    }

  const __bf16* aPtr = act + ((size_t)(b * Tt + t0 + sr)) * K + sk;
  const __bf16* bPtr = W + (size_t)(n0 + sr) * K + sk;
  const __bf16* gPtr = (EPI == 2) ? (W + (size_t)(NOUT + n0 + sr) * K + sk) : bPtr;

  for (int k0 = 0; k0 < K; k0 += 32) {
    uint4 a0 = *(const uint4*)(aPtr + k0);
    uint4 a1 = *(const uint4*)(aPtr + k0 + (size_t)64 * K);
    uint4 w0 = *(const uint4*)(bPtr + k0);
    uint4 w1 = *(const uint4*)(bPtr + k0 + (size_t)64 * K);
    uint4 g0, g1;
    if constexpr (EPI == 2) {
      g0 = *(const uint4*)(gPtr + k0);
      g1 = *(const uint4*)(gPtr + k0 + (size_t)64 * K);
    }
    __syncthreads();
    *(uint4*)&As[sr][sk] = a0; *(uint4*)&As[sr + 64][sk] = a1;
    *(uint4*)&Bs[sr][sk] = w0; *(uint4*)&Bs[sr + 64][sk] = w1;
    if constexpr (EPI == 2) { *(uint4*)&Bs2[sr][sk] = g0; *(uint4*)&Bs2[sr + 64][sk] = g1; }
    __syncthreads();
    bf16x8 af[4], bfr[4], gfr[(EPI == 2) ? 4 : 1];
#pragma unroll
    for (int i = 0; i < 4; i++)
      af[i] = *(const bf16x8*)&As[wm * 64 + i * 16 + l16][quad * 8];
#pragma unroll
    for (int j = 0; j < 4; j++) {
      bfr[j] = *(const bf16x8*)&Bs[wn * 64 + j * 16 + l16][quad * 8];
      if constexpr (EPI == 2)
        gfr[j] = *(const bf16x8*)&Bs2[wn * 64 + j * 16 + l16][quad * 8];
    }
#pragma unroll
    for (int i = 0; i < 4; i++)
#pragma unroll
      for (int j = 0; j < 4; j++) {
        acc[i][j] = __builtin_amdgcn_mfma_f32_16x16x32_bf16(af[i], bfr[j], acc[i][j], 0, 0, 0);
        if constexpr (EPI == 2)
          accg[i][j] = __builtin_amdgcn_mfma_f32_16x16x32_bf16(af[i], gfr[j], accg[i][j], 0, 0, 0);
      }
  }

  // epilogue: D row = t (i*16 + quad*4 + r), col = n (j*16 + l16)
#pragma unroll
  for (int i = 0; i < 4; i++) {
    int tb = t0 + wm * 64 + i * 16 + quad * 4;
    float mv[4];
    if constexpr (EPI == 1) {
#pragma unroll
      for (int r = 0; r < 4; r++) mv[r] = mask[(size_t)b * Tt + tb + r];
    }
#pragma unroll
    for (int j = 0; j < 4; j++) {
      int n = n0 + wn * 64 + j * 16 + l16;
      float bn = bias[n];
      float bg = (EPI == 2) ? bias[NOUT + n] : 0.f;
#pragma unroll
      for (int r = 0; r < 4; r++) {
        size_t o = ((size_t)(b * Tt + tb + r)) * NOUT + n;
        if constexpr (EPI == 0) {
          outf[o] = acc[i][j][r] + bn;
        } else if constexpr (EPI == 1) {
          float v = fmaxf(acc[i][j][r] + bn, 0.f) * mv[r];
          outb[o] = bfbits(v);
        } else {
          float a = acc[i][j][r] + bn;
          float g = accg[i][j][r] + bg;
          outf[o] = a / (1.f + expf(-g));
        }
      }
    }
  }
}

// ---------------- LayerNorm over C (contiguous), wave per row ----------------
__global__ __launch_bounds__(256) void ln_t(
    const float* __restrict__ in1, const float* __restrict__ in2,
    const float* __restrict__ mask, const float* __restrict__ gamma,
    const float* __restrict__ beta, float* __restrict__ out,
    unsigned short* __restrict__ outb, int m1, int m2) {
  int row = blockIdx.x * 4 + (threadIdx.x >> 6);  // b*Tt + t
  int lane = threadIdx.x & 63;
  float mv = mask[row];
  float f1 = m1 ? mv : 1.f;
  float f2 = m2 ? mv : 1.f;
  size_t base = (size_t)row * Hc;
  float v[6], sum = 0.f, sq = 0.f;
#pragma unroll
  for (int j = 0; j < 6; j++) {
    int idx = lane + 64 * j;
    float a = in1[base + idx] * f1 + in2[base + idx] * f2;
    v[j] = a; sum += a; sq = fmaf(a, a, sq);
  }
#pragma unroll
  for (int off = 32; off >= 1; off >>= 1) {
    sum += __shfl_xor(sum, off, 64);
    sq  += __shfl_xor(sq,  off, 64);
  }
  float m = sum * (1.f / Hc);
  float var = sq * (1.f / Hc) - m * m;
  float rs = rsqrtf(var + 1e-4f);
#pragma unroll
  for (int j = 0; j < 6; j++) {
    int idx = lane + 64 * j;
    float o = (v[j] - m) * rs * gamma[idx] + beta[idx];
    out[base + idx] = o;
    if (outb) outb[base + idx] = bfbits(o * mv);
  }
}

// ---------------- diagnostic ----------------
__global__ void diag_kernel(float* out, float v) {
  if (blockIdx.x == 0 && threadIdx.x == 0) out[0] = v;
}

extern "C" void kernel_launch(void* const* d_in, const int* in_sizes, int n_in,
                              void* d_out, int out_size, void* d_ws, size_t ws_size,
                              hipStream_t stream) {
  const float* x_in  = (const float*)d_in[0];
  const float* xmask = (const float*)d_in[1];
  const float* log_dt = (const float*)d_in[2];
  const float* A_re = (const float*)d_in[3];
  const float* A_im = (const float*)d_in[4];
  const float* C_re = (const float*)d_in[5];
  const float* C_im = (const float*)d_in[6];
  const float* Dv   = (const float*)d_in[7];
  const float* Wout = (const float*)d_in[8];
  const float* bout = (const float*)d_in[9];
  const float* g1   = (const float*)d_in[10];
  const float* be1  = (const float*)d_in[11];
  const float* W1   = (const float*)d_in[12];
  const float* bf1  = (const float*)d_in[13];
  const float* W2   = (const float*)d_in[14];
  const float* bf2  = (const float*)d_in[15];
  const float* g2   = (const float*)d_in[16];
  const float* be2  = (const float*)d_in[17];

  const size_t NXf   = (size_t)Bq * Hc * Tt;          // 12,582,912 floats
  const size_t NP    = (size_t)LYR * Hc * N2;         // 73,728
  const size_t YBFf  = NXf / 2;                       // bf16 y / x1b region, in floats
  const size_t HBFf  = (size_t)Bq * Tt * HFq / 2;     // bf16 h region, in floats
  const size_t WOUTf = (size_t)LYR * TWOH * Hc / 2;
  const size_t W1f   = (size_t)LYR * HFq * Hc / 2;
  const size_t W2f   = (size_t)LYR * Hc * HFq / 2;

  size_t need = 2 * NXf + YBFf + HBFf + WOUTf + W1f + W2f + 6 * NP;
  if (ws_size / 4 < need) {
    diag_kernel<<<1, 64, 0, stream>>>((float*)d_out, 1000.0f + (float)(ws_size >> 20));
    return;
  }

  float* ws = (float*)d_ws;
  float* xT   = ws;                       // (B,T,C) fp32 layer state
  float* tmp  = xT + NXf;                 // (B,T,C) fp32: glu out, then ffn2 out
  float* ybfF = tmp + NXf;                // bf16 (B,T,C): y, then x1*mask
  float* hbfF = ybfF + YBFf;              // bf16 (B,T,HF): ffn hidden; scan-states overlay
  float* wobF = hbfF + HBFf;              // bf16 weights
  float* w1bF = wobF + WOUTf;
  float* w2bF = w1bF + W1f;
  float* wre  = w2bF + W2f;
  float* wim  = wre + NP;
  float* cdre = wim + NP;
  float* cdim = cdre + NP;
  float* wSre = cdim + NP;
  float* wSim = wSre + NP;

  unsigned short* ybf = (unsigned short*)ybfF;
  unsigned short* hbf = (unsigned short*)hbfF;
  float* stbuf = hbfF;                    // states overlay (12.6M < 25.2M floats)
  unsigned short* wob = (unsigned short*)wobF;
  unsigned short* w1b = (unsigned short*)w1bF;
  unsigned short* w2b = (unsigned short*)w2bF;
  float* x1 = (float*)d_out;              // (B,T,C) fp32 post-LN1 lives in d_out

  param_kernel<<<(LYR * Hc * N2 + 255) / 256, 256, 0, stream>>>(
      log_dt, A_re, A_im, C_re, C_im, wre, wim, cdre, cdim, wSre, wSim);
  cvt_bf16_kernel<<<(int)(2 * WOUTf + 1023) / 1024, 256, 0, stream>>>(Wout, wob, (int)(WOUTf / 2));
  cvt_bf16_kernel<<<(int)(2 * W1f + 1023) / 1024, 256, 0, stream>>>(W1, w1b, (int)(W1f / 2));
  cvt_bf16_kernel<<<(int)(2 * W2f + 1023) / 1024, 256, 0, stream>>>(W2, w2b, (int)(W2f / 2));
  transpose_fwd<<<dim3(Tt / 32, Hc / 32, Bq), dim3(32, 8), 0, stream>>>(x_in, xT);

  for (int i = 0; i < LYR; i++) {
    size_t po = (size_t)i * Hc * N2;

    scan_local_t<<<dim3(NCH, Hc / 128, Bq), 256, 0, stream>>>(xT, xmask, wre + po, wim + po, stbuf);
    scan_prefix<<<(Bq * Hc * N2) / 256, 256, 0, stream>>>(stbuf, wSre + po, wSim + po);
    scan_out_t<<<dim3(NCH, Hc / 128, Bq), 256, 0, stream>>>(
        xT, xmask, wre + po, wim + po, cdre + po, cdim + po, Dv + (size_t)i * Hc, stbuf, ybf);

    // glu = GLU(Wout*y + bout) -> tmp (fp32)
    mfma_gemm<2><<<dim3(Tt / 128, Hc / 128, Bq), 256, 0, stream>>>(
        (const __bf16*)ybf, (const __bf16*)(wob + (size_t)i * TWOH * Hc),
        bout + (size_t)i * TWOH, xmask, tmp, nullptr, Hc, Hc);

    // x1 = LN(x*mask + glu) -> d_out fp32 ; x1b = bf16(x1*mask) -> ybf
    ln_t<<<(Bq * Tt) / 4, 256, 0, stream>>>(
        xT, tmp, xmask, g1 + (size_t)i * Hc, be1 + (size_t)i * Hc, x1, ybf, 1, 0);

    // h = bf16(relu(W1*x1b + bf1) * mask) -> hbf
    mfma_gemm<1><<<dim3(Tt / 128, HFq / 128, Bq), 256, 0, stream>>>(
        (const __bf16*)ybf, (const __bf16*)(w1b + (size_t)i * HFq * Hc),
        bf1 + (size_t)i * HFq, xmask, nullptr, hbf, Hc, HFq);

    // f = W2*h + bf2 -> tmp (fp32)
    mfma_gemm<0><<<dim3(Tt / 128, Hc / 128, Bq), 256, 0, stream>>>(
        (const __bf16*)hbf, (const __bf16*)(w2b + (size_t)i * Hc * HFq),
        bf2 + (size_t)i * Hc, xmask, tmp, nullptr, HFq, Hc);

    // x = LN(x1 + f*mask) -> xT
    ln_t<<<(Bq * Tt) / 4, 256, 0, stream>>>(
        x1, tmp, xmask, g2 + (size_t)i * Hc, be2 + (size_t)i * Hc, xT, nullptr, 0, 1);
  }

  transpose_bwd<<<dim3(Tt / 32, Hc / 32, Bq), dim3(32, 8), 0, stream>>>(xT, xmask, (float*)d_out);
}